// Round 5
// baseline (93.064 us; speedup 1.0000x reference)
//
#include <hip/hip_runtime.h>
#include <math.h>

#define OUT_H 7
#define OUT_W 7
#define N_C 256
#define FH 38
#define FW 38
#define PLANE (FH * FW)   // 1444
#define NUM_ROIS 256
#define SPATIAL_SCALE 0.0625f

// Channels per block: 4 -> staged LDS 4*1448*4 = 23168 B, total ~27.5 KB,
// 5 blocks/CU resident (25 waves/CU). Grid = 256 rois * 64 chunks = 16384... no:
#define CC 4
#define CHUNKS (N_C / CC)      // 64 -> grid 8192
#define CH_STRIDE 1448         // floats per channel in LDS (1444 padded to x4)

// v5: staged separable ROI max pool.
// Round-4 post-mortem: R3 (scalar loads) and R4 (dwordx2, half the blocks)
// were IDENTICAL to 6ns -> VMEM *instruction count* is not the constraint;
// the divergent multi-row gather (cache-line transactions + L2 latency) is.
// Fix: rows [y1..y2] of one channel are ONE CONTIGUOUS region (<=5.8 KB).
// Stage it to LDS with fully-coalesced float4 loads (every 64B line 100%
// used: ~1.1M lines total vs ~4.8M in R4), then do the divergent separable
// reduction out of LDS where scatter costs banks, not cache lines.
// Bounds safety: y2,x2 <= floor(607.9/16)=37 -> hend,wend <= 38; b in {0,1};
// staging is clamped to the plane end. Both __syncthreads() unconditional.
__global__ __launch_bounds__(266) void roi_pool_kernel(
    const float* __restrict__ feat,
    const float* __restrict__ rois,
    float* __restrict__ out)
{
    __shared__ __align__(16) float chlds[CC][CH_STRIDE];
    __shared__ float rowmax[CC][OUT_H][FW];
    __shared__ int wse[2][OUT_W];

    int blk   = blockIdx.x;
    int r     = blk / CHUNKS;
    int chunk = blk - r * CHUNKS;
    int c0    = chunk * CC;

    // All lanes read the same 5 floats (L1 broadcast); bounds forced scalar.
    const float* roi = rois + r * 5;
    int b  = __builtin_amdgcn_readfirstlane((int)roi[0]);
    int x1 = __builtin_amdgcn_readfirstlane((int)(roi[1] * SPATIAL_SCALE));
    int y1 = __builtin_amdgcn_readfirstlane((int)(roi[2] * SPATIAL_SCALE));
    int x2 = __builtin_amdgcn_readfirstlane((int)(roi[3] * SPATIAL_SCALE));
    int y2 = __builtin_amdgcn_readfirstlane((int)(roi[4] * SPATIAL_SCALE));
    int rh = y2 - y1 + 1;  // >= 1
    int rw = x2 - x1 + 1;  // >= 1

    int tx  = threadIdx.x;               // 0..18 : float2 column pair
    int ty  = threadIdx.y;               // 0..6  : output row bin i
    int tz  = threadIdx.z;               // 0..1  : channel pair select
    int lin = tx + 19 * (ty + 7 * tz);   // 0..265

    // w-bin bounds once (Python floor-div on non-negative == C int div).
    if (lin < OUT_W) {
        wse[0][lin] = x1 + (lin * rw) / OUT_W;
        wse[1][lin] = x1 + ((lin + 1) * rw + OUT_W - 1) / OUT_W;
    }

    // ---- Stage: contiguous region [y1*38 .. (y2+1)*38) per channel ----
    int s0  = (y1 * FW) & ~3;                 // 16B-aligned start (floats)
    int s1  = (y2 + 1) * FW;                  // exclusive end
    int nfl = (s1 - s0 + 3) & ~3;             // padded length
    int pm  = PLANE - s0;                     // clamp to plane end (PLANE%4==0)
    if (nfl > pm) nfl = pm;
    int nf4 = nfl >> 2;                       // float4 chunks, <= 362
    const float* gbase = feat + ((size_t)b * N_C + c0) * PLANE + s0;
    #pragma unroll
    for (int cl = 0; cl < CC; ++cl) {
        for (int k = lin; k < nf4; k += 266) {
            float4 v = *(const float4*)(gbase + cl * PLANE + 4 * k);
            *(float4*)&chlds[cl][4 * k] = v;
        }
    }
    __syncthreads();

    // ---- Phase A: row maxima over h-bins, read from LDS ----
    int i = ty;
    int hstart = y1 + (i * rh) / OUT_H;
    int hend   = y1 + ((i + 1) * rh + OUT_H - 1) / OUT_H;  // > hstart always
    int c2 = tz * 2;
    float2 m0; m0.x = -INFINITY; m0.y = -INFINITY;
    float2 m1 = m0;
    int ofs = hstart * FW + 2 * tx - s0;      // even -> 8B-aligned, >= 0
    for (int h = hstart; h < hend; ++h, ofs += FW) {
        float2 a  = *(const float2*)&chlds[c2 + 0][ofs];
        float2 bb = *(const float2*)&chlds[c2 + 1][ofs];
        m0.x = fmaxf(m0.x, a.x);   m0.y = fmaxf(m0.y, a.y);
        m1.x = fmaxf(m1.x, bb.x);  m1.y = fmaxf(m1.y, bb.y);
    }
    *(float2*)&rowmax[c2 + 0][i][2 * tx] = m0;
    *(float2*)&rowmax[c2 + 1][i][2 * tx] = m1;
    __syncthreads();

    // ---- Phase B: 196 threads, one output each x1 channel decode ----
    if (lin < CC * OUT_H * OUT_W) {           // 196
        int cl  = lin / 49;
        int pos = lin - cl * 49;
        int oi  = pos / OUT_W;
        int j   = pos - oi * OUT_W;
        int ws  = wse[0][j];
        int we  = wse[1][j];                  // > ws always
        float mm = -INFINITY;
        for (int w = ws; w < we; ++w)
            mm = fmaxf(mm, rowmax[cl][oi][w]);
        out[((size_t)r * N_C + c0 + cl) * (OUT_H * OUT_W) + pos] = mm;
    }
}

extern "C" void kernel_launch(void* const* d_in, const int* in_sizes, int n_in,
                              void* d_out, int out_size, void* d_ws, size_t ws_size,
                              hipStream_t stream) {
    const float* feat = (const float*)d_in[0];
    const float* rois = (const float*)d_in[1];
    float* out = (float*)d_out;

    dim3 block(19, OUT_H, 2);        // 266 threads (5 waves)
    int  grid = NUM_ROIS * CHUNKS;   // 8192 blocks
    roi_pool_kernel<<<grid, block, 0, stream>>>(feat, rois, out);
}

// Round 6
// 78.117 us; speedup vs baseline: 1.1913x; 1.1913x over previous
//
#include <hip/hip_runtime.h>
#include <math.h>

#define OUT_H 7
#define OUT_W 7
#define N_C 256
#define FH 38
#define FW 38
#define NUM_ROIS 256
#define SPATIAL_SCALE 0.0625f
#define PLANE (FH * FW)

// Channels per block: 16 -> LDS rowmax = 16*7*38*4 = 17024 B, grid = 4096.
#define CC 16
#define CHUNKS (N_C / CC)

// v6 == v4 restored (best measured: dur_us 77.906).
//
// Session findings leading here:
//  - R1 grid-stride decode was VALU-bound (84% busy): fixed by structural
//    (w,i)=threadIdx map + unrolled register channel dim.
//  - R4 (this kernel) and R3 produced dur_us 6 NANOSECONDS apart across
//    structurally different kernels while harness fills jitter +-0.7us ->
//    dur_us = 77.9 is a saturated harness floor (41.4us poison fill + ~8.4us
//    gaps + ~28us pipeline slack that hides any kernel dispatch below it).
//  - R5 LDS staging (extra pass, 2 barriers, 27.6KB LDS) measured 41.5us and
//    re-surfaced above the floor: staging is net-negative for this shape.
// Therefore: restore the floor-achieving kernel verbatim; further kernel-side
// improvement is unmeasurable in this harness.
//
// Bounds safety: y2,x2 <= floor(607.9*0.0625)=37 -> hend,wend <= 38; b in
// {0,1}. The single __syncthreads() is reached unconditionally.
__global__ __launch_bounds__(266) void roi_pool_kernel(
    const float* __restrict__ feat,
    const float* __restrict__ rois,
    float* __restrict__ out)
{
    __shared__ float rowmax[CC][OUT_H][FW];
    __shared__ int wse[2][OUT_W];

    int blk   = blockIdx.x;
    int r     = blk / CHUNKS;
    int chunk = blk - r * CHUNKS;
    int c0    = chunk * CC;

    // All lanes read the same 5 floats (L1 broadcast); bounds forced scalar.
    const float* roi = rois + r * 5;
    int b  = __builtin_amdgcn_readfirstlane((int)roi[0]);
    int x1 = __builtin_amdgcn_readfirstlane((int)(roi[1] * SPATIAL_SCALE));
    int y1 = __builtin_amdgcn_readfirstlane((int)(roi[2] * SPATIAL_SCALE));
    int x2 = __builtin_amdgcn_readfirstlane((int)(roi[3] * SPATIAL_SCALE));
    int y2 = __builtin_amdgcn_readfirstlane((int)(roi[4] * SPATIAL_SCALE));
    int rh = y2 - y1 + 1;  // >= 1
    int rw = x2 - x1 + 1;  // >= 1

    int tx = threadIdx.x;  // 0..18 : float2 column (w = 2*tx, 2*tx+1)
    int ty = threadIdx.y;  // 0..6  : output row bin i
    int tz = threadIdx.z;  // 0..1  : which 8-channel half
    int lin = tx + 19 * (ty + 7 * tz);  // 0..265

    // w-bin bounds once per block (7 threads), consumed by Phase B after the
    // barrier. Python floor-div on non-negative ints == C int div.
    if (lin < OUT_W) {
        int j = lin;
        wse[0][j] = x1 + (j * rw) / OUT_W;
        wse[1][j] = x1 + ((j + 1) * rw + OUT_W - 1) / OUT_W;
    }

    int i = ty;
    int hstart = y1 + (i * rh) / OUT_H;
    int hend   = y1 + ((i + 1) * rh + OUT_H - 1) / OUT_H;  // > hstart always

    // Uniform (SGPR) channel-group base + vector 32-bit element offset.
    const float* pbase = feat + ((size_t)b * N_C + c0 + tz * 8) * PLANE;
    int off = hstart * FW + 2 * tx;

    float2 m[8];
    #pragma unroll
    for (int cl = 0; cl < 8; ++cl) { m[cl].x = -INFINITY; m[cl].y = -INFINITY; }

    for (int h = hstart; h < hend; ++h, off += FW) {
        #pragma unroll
        for (int cl = 0; cl < 8; ++cl) {
            float2 v = *(const float2*)&pbase[cl * PLANE + off];
            m[cl].x = fmaxf(m[cl].x, v.x);
            m[cl].y = fmaxf(m[cl].y, v.y);
        }
    }

    #pragma unroll
    for (int cl = 0; cl < 8; ++cl)
        *(float2*)&rowmax[tz * 8 + cl][i][2 * tx] = m[cl];  // b64, 2-way = free

    __syncthreads();

    // ---- Phase B: 196 threads, one (i,j) decode amortized over 4 channels ----
    if (lin < 196) {
        int g   = lin / 49;        // channel group 0..3
        int pos = lin - g * 49;    // 0..48
        int oi  = pos / OUT_W;
        int j   = pos - oi * OUT_W;
        int wstart = wse[0][j];
        int wend   = wse[1][j];    // > wstart always
        float* obase = out + ((size_t)r * N_C + c0) * (OUT_H * OUT_W);
        #pragma unroll
        for (int q = 0; q < 4; ++q) {
            int cl = g * 4 + q;
            float mm = -INFINITY;
            for (int ww = wstart; ww < wend; ++ww)
                mm = fmaxf(mm, rowmax[cl][oi][ww]);
            obase[cl * (OUT_H * OUT_W) + pos] = mm;  // 49-float coalesced runs
        }
    }
}

extern "C" void kernel_launch(void* const* d_in, const int* in_sizes, int n_in,
                              void* d_out, int out_size, void* d_ws, size_t ws_size,
                              hipStream_t stream) {
    const float* feat = (const float*)d_in[0];
    const float* rois = (const float*)d_in[1];
    float* out = (float*)d_out;

    dim3 block(19, OUT_H, 2);        // 19*7*2 = 266 threads (5 waves)
    int  grid = NUM_ROIS * CHUNKS;   // 4096 blocks
    roi_pool_kernel<<<grid, block, 0, stream>>>(feat, rois, out);
}